// Round 7
// baseline (285.048 us; speedup 1.0000x reference)
//
#include <hip/hip_runtime.h>

// PlaceCellNetwork forward — R7 ABLATION ROUND.
// R2-R6: five structurally different kernels all ~95-125us while VALUBusy
// swung 35->67% and access pattern swung scattered->dense. No bottom-up model
// explains 100us. So: measure, don't guess. Four full-size dispatches, each
// isolating one axis; per-dispatch durations come back in the rocprof table.
//   k_stream  : pure memory path (dense prev+x read, dense out write)
//   k_comp    : pure compute + real SMEM weight stream (no global I/O)
//   k_nosmem  : full R5 kernel, weights = inline constants (no weight loads)
//   k_full    : correct R5-structure kernel (LAST -> validation passes)
// k_stream/k_nosmem write garbage to out; k_full overwrites everything.

#define HID 20
#define OUT 10
#define RPB 512
#define PSTR 11

typedef float f32x2 __attribute__((ext_vector_type(2)));

__device__ __forceinline__ float fast_rcp(float x) { return __builtin_amdgcn_rcpf(x); }
__device__ __forceinline__ float fast_exp2(float x) { return __builtin_amdgcn_exp2f(x); }
__device__ __forceinline__ f32x2 sp(float s) { return (f32x2){s, s}; }

#define EACH10(F) F(0) F(1) F(2) F(3) F(4) F(5) F(6) F(7) F(8) F(9)
#define PIN(v) asm volatile("" : "+v"(v))

// ---------------- weight providers ----------------
struct WsW {
    const float* w;
    __device__ __forceinline__ float wh(int i, int k) const { return w[24 * i + k]; }
    __device__ __forceinline__ float wf(int i, int o) const { return w[24 * i + 4 + o]; }
    __device__ __forceinline__ float wo(int i, int o) const { return w[24 * i + 14 + o]; }
    __device__ __forceinline__ float linit(int o) const { return w[480 + o]; }
};
struct FakeW {  // values fold to free inline constants (i,o compile-time after unroll)
    __device__ __forceinline__ float pick(int h) const {
        const float v[8] = {0.5f, -0.5f, 1.0f, -1.0f, 2.0f, -2.0f, 4.0f, -4.0f};
        return v[h & 7];
    }
    __device__ __forceinline__ float wh(int i, int k) const { return pick(i * 3 + k * 5); }
    __device__ __forceinline__ float wf(int i, int o) const { return pick(i * 7 + o * 3 + 1); }
    __device__ __forceinline__ float wo(int i, int o) const { return pick(i * 5 + o * 7 + 2); }
    __device__ __forceinline__ float linit(int o) const { return pick(o); }
};

// ---------------- shared compute core (verified math, absmax 2e-3 since R3) ----------------
template <typename W>
__device__ __forceinline__ void pcn_compute(
    const W& wt, const f32x2 x0, const f32x2 x1,
    const f32x2 p0, const f32x2 p1, const f32x2 p2, const f32x2 p3, const f32x2 p4,
    const f32x2 p5, const f32x2 p6, const f32x2 p7, const f32x2 p8, const f32x2 p9,
    f32x2& o0, f32x2& o1, f32x2& o2, f32x2& o3, f32x2& o4,
    f32x2& o5, f32x2& o6, f32x2& o7, f32x2& o8, f32x2& o9) {
#define INITL(o) f32x2 l##o = sp(wt.linit(o));
    EACH10(INITL)
#undef INITL
#pragma unroll
    for (int i = 0; i < HID; ++i) {
        f32x2 a = sp(wt.wh(i, 2));
        a += sp(wt.wh(i, 0)) * x0;
        a += sp(wt.wh(i, 1)) * x1;
#define FB(o) a += sp(wt.wf(i, o)) * p##o;
        EACH10(FB)
#undef FB
        f32x2 r;
        r.x = fast_rcp(1.0f + fast_exp2(a.x));
        r.y = fast_rcp(1.0f + fast_exp2(a.y));
#define LO(o) l##o += sp(wt.wo(i, o)) * r;
        EACH10(LO)
#undef LO
    }
#define EX(o) l##o.x = fast_exp2(l##o.x); l##o.y = fast_exp2(l##o.y);
    EACH10(EX)
#undef EX
    const f32x2 s = ((l0 + l1) + (l2 + l3)) + (((l4 + l5) + (l6 + l7)) + (l8 + l9));
    f32x2 rs;
    rs.x = fast_rcp(s.x);
    rs.y = fast_rcp(s.y);
    o0 = l0 * rs; o1 = l1 * rs; o2 = l2 * rs; o3 = l3 * rs; o4 = l4 * rs;
    o5 = l5 * rs; o6 = l6 * rs; o7 = l7 * rs; o8 = l8 * rs; o9 = l9 * rs;
}

// ---------------- shared R5-structure block body ----------------
template <typename W>
__device__ __forceinline__ void pcn_block_body(
    const W& wt, const float* __restrict__ x, const float* __restrict__ prev,
    float* __restrict__ out, long B) {
    __shared__ float lds[RPB * PSTR];
    const int t = threadIdx.x;
    const long base = (long)blockIdx.x * RPB;
    const int V = (B - base < RPB) ? (int)(B - base) : RPB;
    const int NF = OUT * V;
    const int NF4 = NF >> 2;

    // phase 1: dense global -> LDS transpose stage
    {
        const float4* src = reinterpret_cast<const float4*>(prev + base * OUT);
#pragma unroll
        for (int k = 0; k < 5; ++k) {
            const int idx = t + 256 * k;
            if (idx < NF4) {
                const float4 v = src[idx];
                const float vv[4] = {v.x, v.y, v.z, v.w};
                const int f0 = 4 * idx;
#pragma unroll
                for (int j = 0; j < 4; ++j) {
                    const int f = f0 + j;
                    const int r = f / OUT;
                    lds[PSTR * r + (f - OUT * r)] = vv[j];
                }
            }
        }
        for (int f = (NF4 << 2) + t; f < NF; f += 256) {
            const int r = f / OUT;
            lds[PSTR * r + (f - OUT * r)] = prev[base * OUT + f];
        }
    }
    __syncthreads();

    const bool aok = t < V;
    const bool bok = (t + 256) < V;
    const float* ra = lds + PSTR * t;
    const float* rb = lds + PSTR * (t + 256);

    f32x2 x0, x1;
    {
        f32x2 xa = {0.0f, 0.0f}, xb = {0.0f, 0.0f};
        if (aok) xa = *reinterpret_cast<const f32x2*>(x + 2 * (base + t));
        if (bok) xb = *reinterpret_cast<const f32x2*>(x + 2 * (base + t + 256));
        x0 = (f32x2){xa.x, xb.x};
        x1 = (f32x2){xa.y, xb.y};
    }
#define DECLP(o) f32x2 p##o = {ra[o], rb[o]}; PIN(p##o);
    EACH10(DECLP)
#undef DECLP
    PIN(x0); PIN(x1);

    f32x2 o0, o1, o2, o3, o4, o5, o6, o7, o8, o9;
    pcn_compute(wt, x0, x1, p0, p1, p2, p3, p4, p5, p6, p7, p8, p9,
                o0, o1, o2, o3, o4, o5, o6, o7, o8, o9);

    // phase 4: results -> LDS dense
    __syncthreads();
    if (aok) {
        f32x2* d = reinterpret_cast<f32x2*>(lds + 10 * t);
        d[0] = (f32x2){o0.x, o1.x}; d[1] = (f32x2){o2.x, o3.x};
        d[2] = (f32x2){o4.x, o5.x}; d[3] = (f32x2){o6.x, o7.x};
        d[4] = (f32x2){o8.x, o9.x};
    }
    if (bok) {
        f32x2* d = reinterpret_cast<f32x2*>(lds + 10 * (t + 256));
        d[0] = (f32x2){o0.y, o1.y}; d[1] = (f32x2){o2.y, o3.y};
        d[2] = (f32x2){o4.y, o5.y}; d[3] = (f32x2){o6.y, o7.y};
        d[4] = (f32x2){o8.y, o9.y};
    }
    __syncthreads();

    // phase 5: dense LDS -> global
    {
        float4* dst = reinterpret_cast<float4*>(out + base * OUT);
        const float4* sl = reinterpret_cast<const float4*>(lds);
#pragma unroll
        for (int k = 0; k < 5; ++k) {
            const int idx = t + 256 * k;
            if (idx < NF4) dst[idx] = sl[idx];
        }
        for (int f = (NF4 << 2) + t; f < NF; f += 256) {
            out[base * OUT + f] = lds[f];
        }
    }
}

// ---------------- probe kernels ----------------
// V1: pure memory path. Same bytes as the real kernel, no compute.
__global__ __launch_bounds__(256, 4) void k_stream(
    const float* __restrict__ x, const float* __restrict__ prev,
    float* __restrict__ out, long B) {
    const int t = threadIdx.x;
    const long base = (long)blockIdx.x * RPB;
    const long f4base = base * OUT / 4;
    const long lim4 = (B * OUT) >> 2;
    const long x4base = base * 2 / 4;
    const long xlim4 = (B * 2) >> 2;

    float s = 0.0f;
    if (x4base + t < xlim4) {
        const float4 xv = reinterpret_cast<const float4*>(x)[x4base + t];
        s = (xv.x + xv.y) + (xv.z + xv.w);
    }
    s *= 1e-7f;

    const float4* src = reinterpret_cast<const float4*>(prev) + f4base;
    float4* dst = reinterpret_cast<float4*>(out) + f4base;
#pragma unroll
    for (int k = 0; k < 5; ++k) {
        const int idx = t + 256 * k;
        if (f4base + idx < lim4) {
            float4 v = src[idx];
            v.x = v.x * 1.0000001f + s;
            v.y = v.y * 1.0000001f + s;
            v.z = v.z * 1.0000001f + s;
            v.w = v.w * 1.0000001f + s;
            dst[idx] = v;
        }
    }
}

// V2: pure compute + real SMEM weight stream; no global I/O (asm sink).
__global__ __launch_bounds__(256, 4) void k_comp(const float* __restrict__ w, long B) {
    const long t = (long)blockIdx.x * blockDim.x + threadIdx.x;
    const long r0 = 2 * t;
    if (r0 >= B) return;
    const float fr = (float)(int)(r0 & 4095) * (1.0f / 4096.0f) - 0.5f;
    f32x2 x0 = {fr, fr * 0.25f + 0.1f};
    f32x2 x1 = {fr * 0.5f - 0.2f, fr};
#define DECLP(o) f32x2 p##o = {fr * (0.1f * o + 0.3f), fr * (0.07f * o - 0.2f)};
    EACH10(DECLP)
#undef DECLP
    f32x2 o0, o1, o2, o3, o4, o5, o6, o7, o8, o9;
    WsW wt{w};
    pcn_compute(wt, x0, x1, p0, p1, p2, p3, p4, p5, p6, p7, p8, p9,
                o0, o1, o2, o3, o4, o5, o6, o7, o8, o9);
    f32x2 sink = ((o0 * sp(1.1f) + o1) + (o2 + o3 * sp(0.9f))) +
                 (((o4 + o5) + (o6 * sp(1.3f) + o7)) + (o8 + o9 * sp(0.7f)));
    asm volatile("" :: "v"(sink.x), "v"(sink.y));
}

// V3: full structure, fake inline-constant weights (no weight loads).
__global__ __launch_bounds__(256, 4) void k_nosmem(
    const float* __restrict__ x, const float* __restrict__ prev,
    float* __restrict__ out, long B) {
    FakeW wt;
    pcn_block_body(wt, x, prev, out, B);
}

// V4: the real kernel (R5 structure). MUST BE LAST.
__global__ __launch_bounds__(256, 4) void k_full(
    const float* __restrict__ x, const float* __restrict__ prev,
    const float* __restrict__ w, float* __restrict__ out, long B) {
    WsW wt{w};
    pcn_block_body(wt, x, prev, out, B);
}

// ---- weight repack (verified since R6 layout) ----
__global__ void repack_kernel(const float* __restrict__ Wh, const float* __restrict__ bh,
                              const float* __restrict__ Wo, const float* __restrict__ bo,
                              const float* __restrict__ Wf, float* __restrict__ ws) {
    const float S = 2.8853900817779268f;  // 2*log2(e)
    const float L = 1.4426950408889634f;  // log2(e)
    int t = threadIdx.x;
    if (t < HID) {
        float* b = ws + 24 * t;
        b[0] = S * Wh[3 * t + 0];
        b[1] = S * Wh[3 * t + 1];
        b[2] = S * (Wh[3 * t + 2] + bh[t]);
        b[3] = 0.0f;
        for (int o = 0; o < OUT; ++o) {
            b[4 + o]  = S * Wf[o * HID + t];
            b[14 + o] = -S * Wo[o * HID + t];
        }
    } else if (t < HID + OUT) {
        int o = t - HID;
        float s = bo[o];
        for (int i = 0; i < HID; ++i) s += Wo[o * HID + i];
        ws[480 + o] = L * s;
    }
}

// ---- fallback (no workspace) ----
__global__ __launch_bounds__(256) void pcn_fallback(
    const float* __restrict__ x, const float* __restrict__ prev,
    const float* __restrict__ Wh, const float* __restrict__ bh,
    const float* __restrict__ Wo, const float* __restrict__ bo,
    const float* __restrict__ Wf, float* __restrict__ out, long B) {
    const long r = (long)blockIdx.x * blockDim.x + threadIdx.x;
    if (r >= B) return;
    const float x0 = x[2 * r], x1 = x[2 * r + 1];
#define DECLP(o) float p##o = prev[10 * r + o];
    EACH10(DECLP)
#undef DECLP
#define DECLL(o) float l##o = bo[o];
    EACH10(DECLL)
#undef DECLL
#pragma unroll
    for (int i = 0; i < HID; ++i) {
        float a = fmaf(Wh[3 * i], x0, fmaf(Wh[3 * i + 1], x1, Wh[3 * i + 2] + bh[i]));
#define FB(o) a = fmaf(Wf[o * HID + i], p##o, a);
        EACH10(FB)
#undef FB
        const float h = 1.0f - 2.0f * fast_rcp(1.0f + __expf(2.0f * a));
#define LO(o) l##o = fmaf(Wo[o * HID + i], h, l##o);
        EACH10(LO)
#undef LO
    }
    float m = l0;
#define MX(o) m = fmaxf(m, l##o);
    MX(1) MX(2) MX(3) MX(4) MX(5) MX(6) MX(7) MX(8) MX(9)
#undef MX
    float s = 0.0f;
#define EX(o) l##o = __expf(l##o - m); s += l##o;
    EACH10(EX)
#undef EX
    const float rs = fast_rcp(s);
#define ST(o) out[10 * r + o] = l##o * rs;
    EACH10(ST)
#undef ST
}

extern "C" void kernel_launch(void* const* d_in, const int* in_sizes, int n_in,
                              void* d_out, int out_size, void* d_ws, size_t ws_size,
                              hipStream_t stream) {
    const float* x    = (const float*)d_in[0];
    const float* prev = (const float*)d_in[1];
    const float* Wh   = (const float*)d_in[2];
    const float* bh   = (const float*)d_in[3];
    const float* Wo   = (const float*)d_in[4];
    const float* bo   = (const float*)d_in[5];
    const float* Wf   = (const float*)d_in[6];
    float* out = (float*)d_out;

    const long B = in_sizes[0] / 2;
    const int grid = (int)((B + RPB - 1) / RPB);

    if (ws_size >= 490 * sizeof(float)) {
        float* ws = (float*)d_ws;
        repack_kernel<<<1, 64, 0, stream>>>(Wh, bh, Wo, bo, Wf, ws);
        k_stream<<<grid, 256, 0, stream>>>(x, prev, out, B);
        k_comp<<<(int)((B / 2 + 255) / 256), 256, 0, stream>>>(ws, B);
        k_nosmem<<<grid, 256, 0, stream>>>(x, prev, out, B);
        k_full<<<grid, 256, 0, stream>>>(x, prev, ws, out, B);   // correct, last
    } else {
        const int gb = (int)((B + 255) / 256);
        pcn_fallback<<<gb, 256, 0, stream>>>(x, prev, Wh, bh, Wo, bo, Wf, out, B);
    }
}

// Round 8
// 83.712 us; speedup vs baseline: 3.4051x; 3.4051x over previous
//
#include <hip/hip_runtime.h>

// PlaceCellNetwork forward: out = softmax(tanh([x,1] @ Wh^T + bh + prev @ Wf) @ Wo^T + bo)
// B=4M, IN=2, HID=20, OUT=10.
//
// R8: R7 ablation showed k_stream (pure memory, no compute/LDS) == k_full
// == ~96us at 2.6 TB/s. Memory path is the wall; compute is 100% hidden.
// FETCH_SIZE=94MB despite inputs (192MB) being identical across graph
// replays -> the 160MB output write stream write-allocates in L2/L3 and
// evicts the L3-resident inputs each replay. Fix: NON-TEMPORAL stores on
// the output path (global_store_dwordx4 nt). Writes stop polluting L3;
// inputs stay resident; DRAM traffic drops from ~250MB to ~160MB+eps.
// Predicted: FETCH < 30MB, dur 95 -> 50-70us. Structure otherwise = R5
// (verified absmax 2e-3): LDS-transpose stage, packed f32x2 compute, dense
// phase-5 copy-out (now NT).
//
// Algebra folded at repack:
//   a'' = 2*log2e*(Wh x + bh + Wf^T prev);  r = rcp(1+2^a'')
//   l'  = log2e*(bo+rowsum(Wo)) - 2*log2e*Wo . r ;  out = 2^l' / sum(2^l')
//   (|l'| < ~12 -> exp2 cannot overflow -> softmax max-pass dropped)

#define HID 20
#define OUT 10
#define RPB 512   // rows per block (256 threads x 2 rows)
#define PSTR 11   // LDS row stride in words (odd -> conflict-free)

typedef float f32x2 __attribute__((ext_vector_type(2)));
typedef float f32x4 __attribute__((ext_vector_type(4)));

__device__ __forceinline__ float fast_rcp(float x) { return __builtin_amdgcn_rcpf(x); }
__device__ __forceinline__ float fast_exp2(float x) { return __builtin_amdgcn_exp2f(x); }
__device__ __forceinline__ f32x2 sp(float s) { return (f32x2){s, s}; }

#define EACH10(F) F(0) F(1) F(2) F(3) F(4) F(5) F(6) F(7) F(8) F(9)
#define PIN(v) asm volatile("" : "+v"(v))

// ---- weight repack: scalar layout, 24 floats per hidden unit ----
// per-i block at ws[24*i]:
//   [0]=S*Wh[i][0] [1]=S*Wh[i][1] [2]=S*(Wh[i][2]+bh[i]) [3]=pad
//   [4+o]=S*Wf[o][i]   [14+o]=-S*Wo[o][i]
// ws[480+o] = L*(bo[o]+sum_i Wo[o][i]) ;  S=2*log2e, L=log2e
__global__ void repack_kernel(const float* __restrict__ Wh, const float* __restrict__ bh,
                              const float* __restrict__ Wo, const float* __restrict__ bo,
                              const float* __restrict__ Wf, float* __restrict__ ws) {
    const float S = 2.8853900817779268f;  // 2*log2(e)
    const float L = 1.4426950408889634f;  // log2(e)
    int t = threadIdx.x;
    if (t < HID) {
        float* b = ws + 24 * t;
        b[0] = S * Wh[3 * t + 0];
        b[1] = S * Wh[3 * t + 1];
        b[2] = S * (Wh[3 * t + 2] + bh[t]);
        b[3] = 0.0f;
        for (int o = 0; o < OUT; ++o) {
            b[4 + o]  = S * Wf[o * HID + t];
            b[14 + o] = -S * Wo[o * HID + t];
        }
    } else if (t < HID + OUT) {
        int o = t - HID;
        float s = bo[o];
        for (int i = 0; i < HID; ++i) s += Wo[o * HID + i];
        ws[480 + o] = L * s;
    }
}

// ---- main kernel: R5 structure + non-temporal output stores ----
__global__ __launch_bounds__(256, 4) void pcn_kernel(
    const float* __restrict__ x, const float* __restrict__ prev,
    const float* __restrict__ w, float* __restrict__ out, long B) {
    __shared__ float lds[RPB * PSTR];   // 22528 B
    const int t = threadIdx.x;
    const long base = (long)blockIdx.x * RPB;
    const int V = (B - base < RPB) ? (int)(B - base) : RPB;
    const int NF = OUT * V;
    const int NF4 = NF >> 2;

    // phase 1: dense global -> LDS transpose stage of prev (cached loads:
    // we WANT prev resident in L3 across replays)
    {
        const float4* src = reinterpret_cast<const float4*>(prev + base * OUT);
#pragma unroll
        for (int k = 0; k < 5; ++k) {
            const int idx = t + 256 * k;
            if (idx < NF4) {
                const float4 v = src[idx];
                const float vv[4] = {v.x, v.y, v.z, v.w};
                const int f0 = 4 * idx;
#pragma unroll
                for (int j = 0; j < 4; ++j) {
                    const int f = f0 + j;
                    const int r = f / OUT;           // magic-mul
                    lds[PSTR * r + (f - OUT * r)] = vv[j];
                }
            }
        }
        for (int f = (NF4 << 2) + t; f < NF; f += 256) {
            const int r = f / OUT;
            lds[PSTR * r + (f - OUT * r)] = prev[base * OUT + f];
        }
    }
    __syncthreads();

    // phase 2: per-thread rows from LDS + dense x loads
    const bool aok = t < V;
    const bool bok = (t + 256) < V;
    const float* ra = lds + PSTR * t;
    const float* rb = lds + PSTR * (t + 256);

    f32x2 x0, x1;
    {
        f32x2 xa = {0.0f, 0.0f}, xb = {0.0f, 0.0f};
        if (aok) xa = *reinterpret_cast<const f32x2*>(x + 2 * (base + t));
        if (bok) xb = *reinterpret_cast<const f32x2*>(x + 2 * (base + t + 256));
        x0 = (f32x2){xa.x, xb.x};
        x1 = (f32x2){xa.y, xb.y};
    }
#define DECLP(o) f32x2 p##o = {ra[o], rb[o]}; PIN(p##o);
    EACH10(DECLP)
#undef DECLP
    PIN(x0); PIN(x1);

    // phase 3: packed f32x2 compute (verified core)
#define INITL(o) f32x2 l##o = sp(w[480 + o]);
    EACH10(INITL)
#undef INITL
#pragma unroll
    for (int i = 0; i < HID; ++i) {
        const float* wb = w + 24 * i;
        f32x2 a = sp(wb[2]);
        a += sp(wb[0]) * x0;
        a += sp(wb[1]) * x1;
#define FB(o) a += sp(wb[4 + o]) * p##o;
        EACH10(FB)
#undef FB
        f32x2 r;
        r.x = fast_rcp(1.0f + fast_exp2(a.x));
        r.y = fast_rcp(1.0f + fast_exp2(a.y));
#define LO(o) l##o += sp(wb[14 + o]) * r;
        EACH10(LO)
#undef LO
    }
#define EX(o) l##o.x = fast_exp2(l##o.x); l##o.y = fast_exp2(l##o.y);
    EACH10(EX)
#undef EX
    const f32x2 s = ((l0 + l1) + (l2 + l3)) + (((l4 + l5) + (l6 + l7)) + (l8 + l9));
    f32x2 rs;
    rs.x = fast_rcp(s.x);
    rs.y = fast_rcp(s.y);
#define SC(o) l##o *= rs;
    EACH10(SC)
#undef SC

    // phase 4: results -> LDS dense
    __syncthreads();
    if (aok) {
        f32x2* d = reinterpret_cast<f32x2*>(lds + 10 * t);
        d[0] = (f32x2){l0.x, l1.x}; d[1] = (f32x2){l2.x, l3.x};
        d[2] = (f32x2){l4.x, l5.x}; d[3] = (f32x2){l6.x, l7.x};
        d[4] = (f32x2){l8.x, l9.x};
    }
    if (bok) {
        f32x2* d = reinterpret_cast<f32x2*>(lds + 10 * (t + 256));
        d[0] = (f32x2){l0.y, l1.y}; d[1] = (f32x2){l2.y, l3.y};
        d[2] = (f32x2){l4.y, l5.y}; d[3] = (f32x2){l6.y, l7.y};
        d[4] = (f32x2){l8.y, l9.y};
    }
    __syncthreads();

    // phase 5: dense LDS -> global, NON-TEMPORAL (don't pollute L3; the
    // inputs must stay resident across graph replays)
    {
        f32x4* dst = reinterpret_cast<f32x4*>(out + base * OUT);
        const f32x4* sl = reinterpret_cast<const f32x4*>(lds);
#pragma unroll
        for (int k = 0; k < 5; ++k) {
            const int idx = t + 256 * k;
            if (idx < NF4) {
                __builtin_nontemporal_store(sl[idx], dst + idx);
            }
        }
        for (int f = (NF4 << 2) + t; f < NF; f += 256) {
            __builtin_nontemporal_store(lds[f], out + base * OUT + f);
        }
    }
}

// ---- fallback (no workspace): 1 row/thread ----
__global__ __launch_bounds__(256) void pcn_fallback(
    const float* __restrict__ x, const float* __restrict__ prev,
    const float* __restrict__ Wh, const float* __restrict__ bh,
    const float* __restrict__ Wo, const float* __restrict__ bo,
    const float* __restrict__ Wf, float* __restrict__ out, long B) {
    const long r = (long)blockIdx.x * blockDim.x + threadIdx.x;
    if (r >= B) return;
    const float x0 = x[2 * r], x1 = x[2 * r + 1];
#define DECLP(o) float p##o = prev[10 * r + o];
    EACH10(DECLP)
#undef DECLP
#define DECLL(o) float l##o = bo[o];
    EACH10(DECLL)
#undef DECLL
#pragma unroll
    for (int i = 0; i < HID; ++i) {
        float a = fmaf(Wh[3 * i], x0, fmaf(Wh[3 * i + 1], x1, Wh[3 * i + 2] + bh[i]));
#define FB(o) a = fmaf(Wf[o * HID + i], p##o, a);
        EACH10(FB)
#undef FB
        const float h = 1.0f - 2.0f * fast_rcp(1.0f + __expf(2.0f * a));
#define LO(o) l##o = fmaf(Wo[o * HID + i], h, l##o);
        EACH10(LO)
#undef LO
    }
    float m = l0;
#define MX(o) m = fmaxf(m, l##o);
    MX(1) MX(2) MX(3) MX(4) MX(5) MX(6) MX(7) MX(8) MX(9)
#undef MX
    float s = 0.0f;
#define EX(o) l##o = __expf(l##o - m); s += l##o;
    EACH10(EX)
#undef EX
    const float rs = fast_rcp(s);
#define ST(o) out[10 * r + o] = l##o * rs;
    EACH10(ST)
#undef ST
}

extern "C" void kernel_launch(void* const* d_in, const int* in_sizes, int n_in,
                              void* d_out, int out_size, void* d_ws, size_t ws_size,
                              hipStream_t stream) {
    const float* x    = (const float*)d_in[0];
    const float* prev = (const float*)d_in[1];
    const float* Wh   = (const float*)d_in[2];
    const float* bh   = (const float*)d_in[3];
    const float* Wo   = (const float*)d_in[4];
    const float* bo   = (const float*)d_in[5];
    const float* Wf   = (const float*)d_in[6];
    float* out = (float*)d_out;

    const long B = in_sizes[0] / 2;

    if (ws_size >= 490 * sizeof(float)) {
        float* ws = (float*)d_ws;
        repack_kernel<<<1, 64, 0, stream>>>(Wh, bh, Wo, bo, Wf, ws);
        const int grid = (int)((B + RPB - 1) / RPB);
        pcn_kernel<<<grid, 256, 0, stream>>>(x, prev, ws, out, B);
    } else {
        const int gb = (int)((B + 255) / 256);
        pcn_fallback<<<gb, 256, 0, stream>>>(x, prev, Wh, bh, Wo, bo, Wf, out, B);
    }
}